// Round 16
// baseline (56.545 us; speedup 1.0000x reference)
//
#include <hip/hip_runtime.h>
#include <stdint.h>

#define NB 512      // batch
#define NFEAT 8192
#define NG 512      // groups
#define GG 64      // gather size / K
#define DD 128      // out features per group

typedef short bf16x8 __attribute__((ext_vector_type(8)));
typedef float f32x4 __attribute__((ext_vector_type(4)));
typedef unsigned int u32x4 __attribute__((ext_vector_type(4)));
typedef unsigned short u16;
typedef unsigned int u32;

__device__ __forceinline__ u16 f2bf(float f) {
  unsigned u = __builtin_bit_cast(unsigned, f);
  u += 0x7FFFu + ((u >> 16) & 1u);   // RNE
  return (u16)(u >> 16);
}

// Fused prep.
// Blocks [0,1024): xTb pair-interleaved transpose: for each c, the 64-b tile
// stores u32 pairs (b, b+16) within each 32-b group:
//   u32pos(b) = (b>>5)*16 + (b&15)   [holds rows b (lo16) and b+16 (hi16)]
// Blocks [1024,1536): Wt[n][d][g] = bf16(W[n][g][d]).
__global__ __launch_bounds__(256) void prep_fused(const float* __restrict__ x,
                                                  u32* __restrict__ xTb32,
                                                  const float* __restrict__ W,
                                                  u16* __restrict__ Wt) {
  __shared__ __attribute__((aligned(16))) char lds[18432];
  const int bid = blockIdx.x;
  const int tid = threadIdx.x;
  if (bid < 1024) {
    float (*t)[65] = (float (*)[65])lds;           // [c-local][b-local]
    const int c0 = (bid & 127) * 64;
    const int b0 = (bid >> 7) * 64;
    const int col = tid & 63;
    const int rg = tid >> 6;
    #pragma unroll
    for (int r = 0; r < 16; ++r) {
      int row = rg * 16 + r;          // b-local
      t[col][row] = x[(size_t)(b0 + row) * NFEAT + c0 + col];
    }
    __syncthreads();
    // paired stores: thread's cols c and c+16 pack into one u32 at pos sc
    const int sc = tid & 31;
    const int c = (sc & 15) + ((sc >> 4) << 5);    // 0..15, 32..47
    const int srg = tid >> 5;         // 0..7
    #pragma unroll
    for (int r = 0; r < 8; ++r) {
      int crow = srg * 8 + r;         // c-local
      unsigned px = (unsigned)f2bf(t[crow][c]) |
                    ((unsigned)f2bf(t[crow][c + 16]) << 16);
      xTb32[(size_t)(c0 + crow) * (NB / 2) + (b0 >> 1) + sc] = px;
    }
  } else {
    u16 (*tl)[GG + 8] = (u16 (*)[GG + 8])lds;      // 128 x 72 u16
    const int n = bid - 1024;
    const float* wn = W + (size_t)n * (GG * DD);
    #pragma unroll
    for (int i = 0; i < 32; ++i) {
      int e = i * 256 + tid;          // coalesced read
      int g = e >> 7, d = e & 127;
      tl[d][g] = f2bf(wn[e]);
    }
    __syncthreads();
    u16* dst = Wt + (size_t)n * (DD * GG);
    const int d = tid >> 1, gh = (tid & 1) * 32;
    const u16* src = &tl[d][gh];
    u32x4 v0 = *(const u32x4*)(src);
    u32x4 v1 = *(const u32x4*)(src + 8);
    u32x4 v2 = *(const u32x4*)(src + 16);
    u32x4 v3 = *(const u32x4*)(src + 24);
    u32x4* dp = (u32x4*)(dst + d * GG + gh);
    dp[0] = v0; dp[1] = v1; dp[2] = v2; dp[3] = v3;
  }
}

// Block = (128 b, group n), XCD-swizzled 1D grid (all 4 b-tiles of n on XCD
// n%8). 4 waves, wave = 32 b (2 m-tiles) x 128 d. No LDS.
// A-frag: 16 u32 paired gathers (one load feeds BOTH m-tiles: lo16 = row
// bb+lm, hi16 = row bb+16+lm). B-frag: bf16x8 from Wt, reused by both
// m-tiles. Shared slot->g map g = ks*32 + q*8 + j; C/D map (m89):
// row=(l>>4)*4+r, col=l&15. LN epilogue with mean subtraction (round-14).
__global__ __launch_bounds__(256) void lc_mfma(
    const u32* __restrict__ xTb32,
    const u16* __restrict__ Wt,
    const int* __restrict__ idx,
    const float* __restrict__ bias,
    const float* __restrict__ gamma,
    const float* __restrict__ beta,
    float* __restrict__ out) {
  const int lin = blockIdx.x;
  const int xcd = lin & 7;
  const int slot = lin >> 3;
  const int n = (slot & 63) * 8 + xcd;   // n % 8 == xcd
  const int b0 = (slot >> 6) * 128;
  const int tid = threadIdx.x;
  const int lane = tid & 63;
  const int w = tid >> 6;            // wave's 32-b slice
  const int q = lane >> 4;
  const int lm = lane & 15;
  const int bb = b0 + w * 32;

  const int* idxn = idx + n * GG;

  // per-lane gather offsets (u32 units) for g = ks*32 + q*8 + j
  int cof[16];
  #pragma unroll
  for (int ks = 0; ks < 2; ++ks) {
    int4 ca = *(const int4*)(idxn + ks * 32 + q * 8);
    int4 cb = *(const int4*)(idxn + ks * 32 + q * 8 + 4);
    cof[ks * 8 + 0] = ca.x * (NB / 2); cof[ks * 8 + 1] = ca.y * (NB / 2);
    cof[ks * 8 + 2] = ca.z * (NB / 2); cof[ks * 8 + 3] = ca.w * (NB / 2);
    cof[ks * 8 + 4] = cb.x * (NB / 2); cof[ks * 8 + 5] = cb.y * (NB / 2);
    cof[ks * 8 + 6] = cb.z * (NB / 2); cof[ks * 8 + 7] = cb.w * (NB / 2);
  }

  // A fragments: paired loads, one u32 per g covers both m-tiles
  const int pairbase = (bb >> 1) + lm;   // u32 pos of pair (bb+lm, bb+16+lm)
  bf16x8 afr[2][2];                  // [ks][mi]
  #pragma unroll
  for (int ks = 0; ks < 2; ++ks) {
    u32 d_[8];
    #pragma unroll
    for (int e = 0; e < 8; ++e)
      d_[e] = xTb32[(size_t)cof[ks * 8 + e] + pairbase];
    unsigned p0[4], p1[4];
    #pragma unroll
    for (int r = 0; r < 4; ++r) {
      u32 a = d_[2 * r], b = d_[2 * r + 1];
      p0[r] = (a & 0xffffu) | (b << 16);           // rows bb+lm
      p1[r] = (a >> 16) | (b & 0xffff0000u);       // rows bb+16+lm
    }
    u32x4 a4; a4.x = p0[0]; a4.y = p0[1]; a4.z = p0[2]; a4.w = p0[3];
    afr[ks][0] = __builtin_bit_cast(bf16x8, a4);
    u32x4 b4; b4.x = p1[0]; b4.y = p1[1]; b4.z = p1[2]; b4.w = p1[3];
    afr[ks][1] = __builtin_bit_cast(bf16x8, b4);
  }

  // B fragments + MFMA: each B-frag feeds both m-tiles
  const u16* wtn = Wt + (size_t)n * (DD * GG);
  f32x4 acc[2][8];                   // [mi][ni]
  #pragma unroll
  for (int mi = 0; mi < 2; ++mi)
    #pragma unroll
    for (int ni = 0; ni < 8; ++ni) acc[mi][ni] = f32x4{0.f, 0.f, 0.f, 0.f};

  #pragma unroll
  for (int ks = 0; ks < 2; ++ks) {
    #pragma unroll
    for (int ni = 0; ni < 8; ++ni) {
      const int d = ni * 16 + lm;
      bf16x8 bfr = *(const bf16x8*)(wtn + d * GG + ks * 32 + q * 8);
      acc[0][ni] = __builtin_amdgcn_mfma_f32_16x16x32_bf16(afr[ks][0], bfr, acc[0][ni], 0, 0, 0);
      acc[1][ni] = __builtin_amdgcn_mfma_f32_16x16x32_bf16(afr[ks][1], bfr, acc[1][ni], 0, 0, 0);
    }
  }

  // epilogue: +bias, LeakyReLU, LN over d (row mi*16+q*4+r in 16 lm-lanes x 8 regs)
  float bv[8], gv[8], tv[8];
  #pragma unroll
  for (int ni = 0; ni < 8; ++ni) {
    const int d = ni * 16 + lm;
    bv[ni] = bias[n * DD + d];
    gv[ni] = gamma[d];
    tv[ni] = beta[d];
  }
  #pragma unroll
  for (int mi = 0; mi < 2; ++mi) {
    #pragma unroll
    for (int r = 0; r < 4; ++r) {
      float h[8];
      float s = 0.f, s2 = 0.f;
      #pragma unroll
      for (int ni = 0; ni < 8; ++ni) {
        float v = acc[mi][ni][r] + bv[ni];
        v = (v >= 0.f) ? v : 0.2f * v;
        h[ni] = v;
        s += v;
        s2 += v * v;
      }
      s  += __shfl_xor(s, 1);  s  += __shfl_xor(s, 2);
      s  += __shfl_xor(s, 4);  s  += __shfl_xor(s, 8);
      s2 += __shfl_xor(s2, 1); s2 += __shfl_xor(s2, 2);
      s2 += __shfl_xor(s2, 4); s2 += __shfl_xor(s2, 8);
      const float mu = s * (1.f / 128.f);
      const float var = s2 * (1.f / 128.f) - mu * mu;
      const float rs = rsqrtf(var + 1e-5f);

      const int brow = bb + mi * 16 + q * 4 + r;
      float* ob = out + ((size_t)brow * NG + n) * DD + lm;
      #pragma unroll
      for (int ni = 0; ni < 8; ++ni)
        __builtin_nontemporal_store((h[ni] - mu) * rs * gv[ni] + tv[ni], ob + ni * 16);
    }
  }
}

extern "C" void kernel_launch(void* const* d_in, const int* in_sizes, int n_in,
                              void* d_out, int out_size, void* d_ws, size_t ws_size,
                              hipStream_t stream) {
  const float* x     = (const float*)d_in[0];
  const int*   idx   = (const int*)d_in[1];
  const float* W     = (const float*)d_in[2];
  const float* bias  = (const float*)d_in[3];
  const float* gamma = (const float*)d_in[4];
  const float* beta  = (const float*)d_in[5];
  float* out = (float*)d_out;

  u32* xTb32 = (u32*)d_ws;                         // 8192*256 u32 = 8 MiB
  u16* Wt = (u16*)(xTb32 + (size_t)NFEAT * (NB / 2)); // 8 MiB

  prep_fused<<<1536, 256, 0, stream>>>(x, xTb32, W, Wt);
  lc_mfma<<<2048, 256, 0, stream>>>(xTb32, Wt, idx, bias, gamma, beta, out);
}

// Round 17
// 51.657 us; speedup vs baseline: 1.0946x; 1.0946x over previous
//
#include <hip/hip_runtime.h>
#include <stdint.h>

#define NB 512      // batch
#define NFEAT 8192
#define NG 512      // groups
#define GG 64       // gather size / K
#define DD 128      // out features per group

typedef short bf16x8 __attribute__((ext_vector_type(8)));
typedef float f32x4 __attribute__((ext_vector_type(4)));
typedef unsigned int u32x4 __attribute__((ext_vector_type(4)));
typedef unsigned short u16;
typedef unsigned int u32;

__device__ __forceinline__ u16 f2bf(float f) {
  unsigned u = __builtin_bit_cast(unsigned, f);
  u += 0x7FFFu + ((u >> 16) & 1u);   // RNE
  return (u16)(u >> 16);
}

// Fused prep.
// Blocks [0,1024): xTb pair-interleaved transpose: u32pos(b)=(b>>5)*16+(b&15),
// holding rows b (lo16) and b+16 (hi16).
// Blocks [1024,1536): Wt[n][d][g] = bf16(W[n][g][d]).
__global__ __launch_bounds__(256) void prep_fused(const float* __restrict__ x,
                                                  u32* __restrict__ xTb32,
                                                  const float* __restrict__ W,
                                                  u16* __restrict__ Wt) {
  __shared__ __attribute__((aligned(16))) char lds[18432];
  const int bid = blockIdx.x;
  const int tid = threadIdx.x;
  if (bid < 1024) {
    float (*t)[65] = (float (*)[65])lds;           // [c-local][b-local]
    const int c0 = (bid & 127) * 64;
    const int b0 = (bid >> 7) * 64;
    const int col = tid & 63;
    const int rg = tid >> 6;
    #pragma unroll
    for (int r = 0; r < 16; ++r) {
      int row = rg * 16 + r;          // b-local
      t[col][row] = x[(size_t)(b0 + row) * NFEAT + c0 + col];
    }
    __syncthreads();
    // paired stores: cols c and c+16 pack into one u32 at pos sc
    const int sc = tid & 31;
    const int c = (sc & 15) + ((sc >> 4) << 5);    // 0..15, 32..47
    const int srg = tid >> 5;         // 0..7
    #pragma unroll
    for (int r = 0; r < 8; ++r) {
      int crow = srg * 8 + r;         // c-local
      unsigned px = (unsigned)f2bf(t[crow][c]) |
                    ((unsigned)f2bf(t[crow][c + 16]) << 16);
      xTb32[(size_t)(c0 + crow) * (NB / 2) + (b0 >> 1) + sc] = px;
    }
  } else {
    u16 (*tl)[GG + 8] = (u16 (*)[GG + 8])lds;      // 128 x 72 u16
    const int n = bid - 1024;
    const float* wn = W + (size_t)n * (GG * DD);
    #pragma unroll
    for (int i = 0; i < 32; ++i) {
      int e = i * 256 + tid;          // coalesced read
      int g = e >> 7, d = e & 127;
      tl[d][g] = f2bf(wn[e]);
    }
    __syncthreads();
    u16* dst = Wt + (size_t)n * (DD * GG);
    const int d = tid >> 1, gh = (tid & 1) * 32;
    const u16* src = &tl[d][gh];
    u32x4 v0 = *(const u32x4*)(src);
    u32x4 v1 = *(const u32x4*)(src + 8);
    u32x4 v2 = *(const u32x4*)(src + 16);
    u32x4 v3 = *(const u32x4*)(src + 24);
    u32x4* dp = (u32x4*)(dst + d * GG + gh);
    dp[0] = v0; dp[1] = v1; dp[2] = v2; dp[3] = v3;
  }
}

// Block = (128 b, group n), XCD-swizzled 1D grid (all 4 b-tiles of n on XCD
// n%8). 4 waves, wave = 32 b (2 m-tiles) x 128 d.
// A-frag: 16 paired u32 gathers (one load feeds BOTH m-tiles). B-frag:
// bf16x8 from Wt, reused by both m-tiles. Shared slot->g map
// g = ks*32 + q*8 + j; C/D map (m89): row=(l>>4)*4+r, col=l&15.
// Epilogue: LN in-register, then LDS round-trip so stores are half-wave
// 512 B contiguous NT dwordx4 (16 store instrs/thread instead of 64).
__global__ __launch_bounds__(256) void lc_mfma(
    const u32* __restrict__ xTb32,
    const u16* __restrict__ Wt,
    const int* __restrict__ idx,
    const float* __restrict__ bias,
    const float* __restrict__ gamma,
    const float* __restrict__ beta,
    float* __restrict__ out) {
  __shared__ __attribute__((aligned(16))) float ot[64][130];   // 33 KB

  const int lin = blockIdx.x;
  const int xcd = lin & 7;
  const int slot = lin >> 3;
  const int n = (slot & 63) * 8 + xcd;   // n % 8 == xcd
  const int b0 = (slot >> 6) * 128;
  const int tid = threadIdx.x;
  const int lane = tid & 63;
  const int w = tid >> 6;            // wave's 32-b slice
  const int q = lane >> 4;
  const int lm = lane & 15;
  const int bb = b0 + w * 32;

  const int* idxn = idx + n * GG;

  // per-lane gather offsets (u32 units) for g = ks*32 + q*8 + j
  int cof[16];
  #pragma unroll
  for (int ks = 0; ks < 2; ++ks) {
    int4 ca = *(const int4*)(idxn + ks * 32 + q * 8);
    int4 cb = *(const int4*)(idxn + ks * 32 + q * 8 + 4);
    cof[ks * 8 + 0] = ca.x * (NB / 2); cof[ks * 8 + 1] = ca.y * (NB / 2);
    cof[ks * 8 + 2] = ca.z * (NB / 2); cof[ks * 8 + 3] = ca.w * (NB / 2);
    cof[ks * 8 + 4] = cb.x * (NB / 2); cof[ks * 8 + 5] = cb.y * (NB / 2);
    cof[ks * 8 + 6] = cb.z * (NB / 2); cof[ks * 8 + 7] = cb.w * (NB / 2);
  }

  // A fragments: paired loads, one u32 per g covers both m-tiles
  const int pairbase = (bb >> 1) + lm;   // u32 pos of pair (bb+lm, bb+16+lm)
  bf16x8 afr[2][2];                  // [ks][mi]
  #pragma unroll
  for (int ks = 0; ks < 2; ++ks) {
    u32 d_[8];
    #pragma unroll
    for (int e = 0; e < 8; ++e)
      d_[e] = xTb32[(size_t)cof[ks * 8 + e] + pairbase];
    unsigned p0[4], p1[4];
    #pragma unroll
    for (int r = 0; r < 4; ++r) {
      u32 a = d_[2 * r], b = d_[2 * r + 1];
      p0[r] = (a & 0xffffu) | (b << 16);           // rows bb+lm
      p1[r] = (a >> 16) | (b & 0xffff0000u);       // rows bb+16+lm
    }
    u32x4 a4; a4.x = p0[0]; a4.y = p0[1]; a4.z = p0[2]; a4.w = p0[3];
    afr[ks][0] = __builtin_bit_cast(bf16x8, a4);
    u32x4 b4; b4.x = p1[0]; b4.y = p1[1]; b4.z = p1[2]; b4.w = p1[3];
    afr[ks][1] = __builtin_bit_cast(bf16x8, b4);
  }

  // B fragments + MFMA: each B-frag feeds both m-tiles
  const u16* wtn = Wt + (size_t)n * (DD * GG);
  f32x4 acc[2][8];                   // [mi][ni]
  #pragma unroll
  for (int mi = 0; mi < 2; ++mi)
    #pragma unroll
    for (int ni = 0; ni < 8; ++ni) acc[mi][ni] = f32x4{0.f, 0.f, 0.f, 0.f};

  #pragma unroll
  for (int ks = 0; ks < 2; ++ks) {
    #pragma unroll
    for (int ni = 0; ni < 8; ++ni) {
      const int d = ni * 16 + lm;
      bf16x8 bfr = *(const bf16x8*)(wtn + d * GG + ks * 32 + q * 8);
      acc[0][ni] = __builtin_amdgcn_mfma_f32_16x16x32_bf16(afr[ks][0], bfr, acc[0][ni], 0, 0, 0);
      acc[1][ni] = __builtin_amdgcn_mfma_f32_16x16x32_bf16(afr[ks][1], bfr, acc[1][ni], 0, 0, 0);
    }
  }

  // epilogue: +bias, LeakyReLU, LN over d (row mi*16+q*4+r in 16 lm-lanes x 8 regs)
  float bv[8], gv[8], tv[8];
  #pragma unroll
  for (int ni = 0; ni < 8; ++ni) {
    const int d = ni * 16 + lm;
    bv[ni] = bias[n * DD + d];
    gv[ni] = gamma[d];
    tv[ni] = beta[d];
  }
  const int hv = lane >> 5;          // half-wave
  const int dl = (lane & 31) * 4;    // dword offset within row
  #pragma unroll
  for (int mi = 0; mi < 2; ++mi) {
    #pragma unroll
    for (int r = 0; r < 4; ++r) {
      float h[8];
      float s = 0.f, s2 = 0.f;
      #pragma unroll
      for (int ni = 0; ni < 8; ++ni) {
        float v = acc[mi][ni][r] + bv[ni];
        v = (v >= 0.f) ? v : 0.2f * v;
        h[ni] = v;
        s += v;
        s2 += v * v;
      }
      s  += __shfl_xor(s, 1);  s  += __shfl_xor(s, 2);
      s  += __shfl_xor(s, 4);  s  += __shfl_xor(s, 8);
      s2 += __shfl_xor(s2, 1); s2 += __shfl_xor(s2, 2);
      s2 += __shfl_xor(s2, 4); s2 += __shfl_xor(s2, 8);
      const float mu = s * (1.f / 128.f);
      const float var = s2 * (1.f / 128.f) - mu * mu;
      const float rs = rsqrtf(var + 1e-5f);

      // stage to LDS in MFMA layout (2-way banks max = free)
      float* orow = &ot[w * 16 + q * 4 + r][lm];
      #pragma unroll
      for (int ni = 0; ni < 8; ++ni)
        orow[ni * 16] = (h[ni] - mu) * rs * gv[ni] + tv[ni];
    }
    __syncthreads();
    // coalesced flush: half-wave = one full 512 B row per store instr
    #pragma unroll
    for (int i = 0; i < 8; ++i) {
      const int rho = i * 8 + w * 2 + hv;          // pass-local row
      const int grow = b0 + (rho >> 4) * 32 + mi * 16 + (rho & 15);
      f32x4 v = *(const f32x4*)&ot[rho][dl];
      __builtin_nontemporal_store(v, (f32x4*)(out + ((size_t)grow * NG + n) * DD + dl));
    }
    __syncthreads();
  }
}

extern "C" void kernel_launch(void* const* d_in, const int* in_sizes, int n_in,
                              void* d_out, int out_size, void* d_ws, size_t ws_size,
                              hipStream_t stream) {
  const float* x     = (const float*)d_in[0];
  const int*   idx   = (const int*)d_in[1];
  const float* W     = (const float*)d_in[2];
  const float* bias  = (const float*)d_in[3];
  const float* gamma = (const float*)d_in[4];
  const float* beta  = (const float*)d_in[5];
  float* out = (float*)d_out;

  u32* xTb32 = (u32*)d_ws;                         // 8192*256 u32 = 8 MiB
  u16* Wt = (u16*)(xTb32 + (size_t)NFEAT * (NB / 2)); // 8 MiB

  prep_fused<<<1536, 256, 0, stream>>>(x, xTb32, W, Wt);
  lc_mfma<<<2048, 256, 0, stream>>>(xTb32, Wt, idx, bias, gamma, beta, out);
}

// Round 18
// 51.611 us; speedup vs baseline: 1.0956x; 1.0009x over previous
//
#include <hip/hip_runtime.h>
#include <stdint.h>

#define NB 512      // batch
#define NFEAT 8192
#define NG 512      // groups
#define GG 64       // gather size / K
#define DD 128      // out features per group

typedef short bf16x8 __attribute__((ext_vector_type(8)));
typedef float f32x4 __attribute__((ext_vector_type(4)));
typedef unsigned int u32x4 __attribute__((ext_vector_type(4)));
typedef unsigned short u16;
typedef unsigned int u32;

__device__ __forceinline__ u16 f2bf(float f) {
  unsigned u = __builtin_bit_cast(unsigned, f);
  u += 0x7FFFu + ((u >> 16) & 1u);   // RNE
  return (u16)(u >> 16);
}

// Fused prep.
// Blocks [0,1024): xTb pair-interleaved transpose: u32pos(b)=(b>>5)*16+(b&15),
// holding rows b (lo16) and b+16 (hi16).
// Blocks [1024,1536): Wt[n][d][g] = bf16(W[n][g][d]).
__global__ __launch_bounds__(256) void prep_fused(const float* __restrict__ x,
                                                  u32* __restrict__ xTb32,
                                                  const float* __restrict__ W,
                                                  u16* __restrict__ Wt) {
  __shared__ __attribute__((aligned(16))) char lds[18432];
  const int bid = blockIdx.x;
  const int tid = threadIdx.x;
  if (bid < 1024) {
    float (*t)[65] = (float (*)[65])lds;           // [c-local][b-local]
    const int c0 = (bid & 127) * 64;
    const int b0 = (bid >> 7) * 64;
    const int col = tid & 63;
    const int rg = tid >> 6;
    #pragma unroll
    for (int r = 0; r < 16; ++r) {
      int row = rg * 16 + r;          // b-local
      t[col][row] = x[(size_t)(b0 + row) * NFEAT + c0 + col];
    }
    __syncthreads();
    // paired stores: cols c and c+16 pack into one u32 at pos sc
    const int sc = tid & 31;
    const int c = (sc & 15) + ((sc >> 4) << 5);    // 0..15, 32..47
    const int srg = tid >> 5;         // 0..7
    #pragma unroll
    for (int r = 0; r < 8; ++r) {
      int crow = srg * 8 + r;         // c-local
      unsigned px = (unsigned)f2bf(t[crow][c]) |
                    ((unsigned)f2bf(t[crow][c + 16]) << 16);
      xTb32[(size_t)(c0 + crow) * (NB / 2) + (b0 >> 1) + sc] = px;
    }
  } else {
    u16 (*tl)[GG + 8] = (u16 (*)[GG + 8])lds;      // 128 x 72 u16
    const int n = bid - 1024;
    const float* wn = W + (size_t)n * (GG * DD);
    #pragma unroll
    for (int i = 0; i < 32; ++i) {
      int e = i * 256 + tid;          // coalesced read
      int g = e >> 7, d = e & 127;
      tl[d][g] = f2bf(wn[e]);
    }
    __syncthreads();
    u16* dst = Wt + (size_t)n * (DD * GG);
    const int d = tid >> 1, gh = (tid & 1) * 32;
    const u16* src = &tl[d][gh];
    u32x4 v0 = *(const u32x4*)(src);
    u32x4 v1 = *(const u32x4*)(src + 8);
    u32x4 v2 = *(const u32x4*)(src + 16);
    u32x4 v3 = *(const u32x4*)(src + 24);
    u32x4* dp = (u32x4*)(dst + d * GG + gh);
    dp[0] = v0; dp[1] = v1; dp[2] = v2; dp[3] = v3;
  }
}

// Block = (256 b super-tile, group n), XCD-swizzled 1D grid (n%8 == XCD);
// 1024 blocks = fully resident (4/CU, LDS-limited). Two sequential 128-b
// passes per block: idx/cof/bias/gamma/beta loaded once; pass-2 A-gathers
// issue right after pass-1 MFMA so their latency hides under pass-1's
// epilogue + store drain. Per pass: 4 waves, wave = 32 b (2 m-tiles) x 128 d.
// A-frag: paired u32 gathers (one load feeds both m-tiles). B-frag: bf16x8
// from Wt (L2-hit), reloaded per pass. Shared slot->g map g = ks*32+q*8+j;
// C/D map (m89): row=(l>>4)*4+r, col=l&15. Epilogue: LN in-register, LDS
// round-trip, half-wave 512 B contiguous NT dwordx4 flush.
__global__ __launch_bounds__(256) void lc_mfma(
    const u32* __restrict__ xTb32,
    const u16* __restrict__ Wt,
    const int* __restrict__ idx,
    const float* __restrict__ bias,
    const float* __restrict__ gamma,
    const float* __restrict__ beta,
    float* __restrict__ out) {
  __shared__ __attribute__((aligned(16))) float ot[64][130];   // 33 KB

  const int lin = blockIdx.x;          // [0,1024)
  const int xcd = lin & 7;
  const int slot = lin >> 3;           // [0,128)
  const int n = (slot & 63) * 8 + xcd; // n % 8 == xcd
  const int b0s = (slot >> 6) * 256;   // 256-b super-tile base
  const int tid = threadIdx.x;
  const int lane = tid & 63;
  const int w = tid >> 6;
  const int q = lane >> 4;
  const int lm = lane & 15;
  const int hv = lane >> 5;            // half-wave
  const int dl = (lane & 31) * 4;      // dword offset within out row

  const int* idxn = idx + n * GG;
  const u16* wtn = Wt + (size_t)n * (DD * GG);

  // per-lane gather offsets (u32 units) for g = ks*32 + q*8 + j — shared by both passes
  int cof[16];
  #pragma unroll
  for (int ks = 0; ks < 2; ++ks) {
    int4 ca = *(const int4*)(idxn + ks * 32 + q * 8);
    int4 cb = *(const int4*)(idxn + ks * 32 + q * 8 + 4);
    cof[ks * 8 + 0] = ca.x * (NB / 2); cof[ks * 8 + 1] = ca.y * (NB / 2);
    cof[ks * 8 + 2] = ca.z * (NB / 2); cof[ks * 8 + 3] = ca.w * (NB / 2);
    cof[ks * 8 + 4] = cb.x * (NB / 2); cof[ks * 8 + 5] = cb.y * (NB / 2);
    cof[ks * 8 + 6] = cb.z * (NB / 2); cof[ks * 8 + 7] = cb.w * (NB / 2);
  }

  auto gather = [&](u32 (&d_)[16], int pairbase) {
    #pragma unroll
    for (int e = 0; e < 16; ++e)
      d_[e] = xTb32[(size_t)cof[e] + pairbase];
  };

  // repack paired u32s -> A-frags, load B-frags, run MFMAs
  auto pass_mfma = [&](const u32 (&d_)[16], f32x4 (&acc)[2][8]) {
    #pragma unroll
    for (int mi = 0; mi < 2; ++mi)
      #pragma unroll
      for (int ni = 0; ni < 8; ++ni) acc[mi][ni] = f32x4{0.f, 0.f, 0.f, 0.f};
    #pragma unroll
    for (int ks = 0; ks < 2; ++ks) {
      unsigned p0[4], p1[4];
      #pragma unroll
      for (int r = 0; r < 4; ++r) {
        u32 a = d_[ks * 8 + 2 * r], b = d_[ks * 8 + 2 * r + 1];
        p0[r] = (a & 0xffffu) | (b << 16);           // rows bb+lm
        p1[r] = (a >> 16) | (b & 0xffff0000u);       // rows bb+16+lm
      }
      u32x4 a4; a4.x = p0[0]; a4.y = p0[1]; a4.z = p0[2]; a4.w = p0[3];
      bf16x8 af0 = __builtin_bit_cast(bf16x8, a4);
      u32x4 b4; b4.x = p1[0]; b4.y = p1[1]; b4.z = p1[2]; b4.w = p1[3];
      bf16x8 af1 = __builtin_bit_cast(bf16x8, b4);
      #pragma unroll
      for (int ni = 0; ni < 8; ++ni) {
        const int d = ni * 16 + lm;
        bf16x8 bfr = *(const bf16x8*)(wtn + d * GG + ks * 32 + q * 8);
        acc[0][ni] = __builtin_amdgcn_mfma_f32_16x16x32_bf16(af0, bfr, acc[0][ni], 0, 0, 0);
        acc[1][ni] = __builtin_amdgcn_mfma_f32_16x16x32_bf16(af1, bfr, acc[1][ni], 0, 0, 0);
      }
    }
  };

  // bias / gamma / beta once (used by both passes)
  float bv[8], gv[8], tv[8];
  #pragma unroll
  for (int ni = 0; ni < 8; ++ni) {
    const int d = ni * 16 + lm;
    bv[ni] = bias[n * DD + d];
    gv[ni] = gamma[d];
    tv[ni] = beta[d];
  }

  auto epilogue = [&](f32x4 (&acc)[2][8], int bbp) {
    #pragma unroll
    for (int mi = 0; mi < 2; ++mi) {
      #pragma unroll
      for (int r = 0; r < 4; ++r) {
        float h[8];
        float s = 0.f, s2 = 0.f;
        #pragma unroll
        for (int ni = 0; ni < 8; ++ni) {
          float v = acc[mi][ni][r] + bv[ni];
          v = (v >= 0.f) ? v : 0.2f * v;
          h[ni] = v;
          s += v;
          s2 += v * v;
        }
        s  += __shfl_xor(s, 1);  s  += __shfl_xor(s, 2);
        s  += __shfl_xor(s, 4);  s  += __shfl_xor(s, 8);
        s2 += __shfl_xor(s2, 1); s2 += __shfl_xor(s2, 2);
        s2 += __shfl_xor(s2, 4); s2 += __shfl_xor(s2, 8);
        const float mu = s * (1.f / 128.f);
        const float var = s2 * (1.f / 128.f) - mu * mu;
        const float rs = rsqrtf(var + 1e-5f);
        float* orow = &ot[w * 16 + q * 4 + r][lm];
        #pragma unroll
        for (int ni = 0; ni < 8; ++ni)
          orow[ni * 16] = (h[ni] - mu) * rs * gv[ni] + tv[ni];
      }
      __syncthreads();
      #pragma unroll
      for (int i = 0; i < 8; ++i) {
        const int rho = i * 8 + w * 2 + hv;          // pass-local row
        const int grow = bbp + (rho >> 4) * 32 + mi * 16 + (rho & 15);
        f32x4 v = *(const f32x4*)&ot[rho][dl];
        __builtin_nontemporal_store(v, (f32x4*)(out + ((size_t)grow * NG + n) * DD + dl));
      }
      __syncthreads();
    }
  };

  // ---- pass 1 ----
  u32 d1_[16], d2_[16];
  gather(d1_, ((b0s + w * 32) >> 1) + lm);
  f32x4 acc[2][8];
  pass_mfma(d1_, acc);
  // issue pass-2 gathers early: latency hides under pass-1 epilogue + drain
  gather(d2_, ((b0s + 128 + w * 32) >> 1) + lm);
  epilogue(acc, b0s);

  // ---- pass 2 ----
  pass_mfma(d2_, acc);
  epilogue(acc, b0s + 128);
}

extern "C" void kernel_launch(void* const* d_in, const int* in_sizes, int n_in,
                              void* d_out, int out_size, void* d_ws, size_t ws_size,
                              hipStream_t stream) {
  const float* x     = (const float*)d_in[0];
  const int*   idx   = (const int*)d_in[1];
  const float* W     = (const float*)d_in[2];
  const float* bias  = (const float*)d_in[3];
  const float* gamma = (const float*)d_in[4];
  const float* beta  = (const float*)d_in[5];
  float* out = (float*)d_out;

  u32* xTb32 = (u32*)d_ws;                         // 8192*256 u32 = 8 MiB
  u16* Wt = (u16*)(xTb32 + (size_t)NFEAT * (NB / 2)); // 8 MiB

  prep_fused<<<1536, 256, 0, stream>>>(x, xTb32, W, Wt);
  lc_mfma<<<1024, 256, 0, stream>>>(xTb32, Wt, idx, bias, gamma, beta, out);
}